// Round 2
// baseline (90.776 us; speedup 1.0000x reference)
//
#include <hip/hip_runtime.h>
#include <hip/hip_bf16.h>
#include <math.h>

// SlowROIPool: adaptive 7x7 max-pool over integer ROI crops.
// images [N=4,C=256,H=50,W=50] f32, rois [R=256,4] f32 normalized, roi_idx [R] i32.
// out [R,C,7,7] f32.
//
// Hardened: scalar rois loads (no float4 cast), all indices clamped so no
// address can ever leave its buffer even if inputs are transiently poisoned,
// writes bounded by harness-provided out_size.

#define S 7
#define NN 4
#define NC 256
#define NH 50
#define NW 50
#define NR 256

__global__ __launch_bounds__(256) void roipool_kernel(
    const float* __restrict__ images,
    const float* __restrict__ rois,
    const int* __restrict__ roi_idx,
    float* __restrict__ out,
    int total)
{
    const int tid = blockIdx.x * blockDim.x + threadIdx.x;
    if (tid >= total) return;

    const int j = tid % S;
    const int i = (tid / S) % S;
    const int c = (tid / (S * S)) % NC;
    const int r = tid / (S * S * NC);

    // Per-ROI box — scalar loads, results clamped to valid ranges.
    const float rx1 = rois[4 * r + 0];
    const float ry1 = rois[4 * r + 1];
    const float rx2 = rois[4 * r + 2];
    const float ry2 = rois[4 * r + 3];
    int x1 = (int)floorf(rx1 * (float)NW);
    int y1 = (int)floorf(ry1 * (float)NH);
    int x2 = (int)ceilf(rx2 * (float)NW);
    int y2 = (int)ceilf(ry2 * (float)NH);
    // clamp: 0 <= x1 < x2 <= NW (identity for all sane inputs)
    x1 = min(max(x1, 0), NW - 1);
    y1 = min(max(y1, 0), NH - 1);
    x2 = min(max(x2, x1 + 1), NW);
    y2 = min(max(y2, y1 + 1), NH);
    const int sw = x2 - x1;
    const int sh = y2 - y1;

    // PyTorch adaptive bins: start = lo + (k*size)/S, end = lo + ceil((k+1)*size/S)
    const int ws = x1 + (j * sw) / S;
    const int we = x1 + ((j + 1) * sw + S - 1) / S;
    const int hs = y1 + (i * sh) / S;
    const int he = y1 + ((i + 1) * sh + S - 1) / S;

    int n = roi_idx[r];
    n = min(max(n, 0), NN - 1);
    const float* __restrict__ base =
        images + ((size_t)(n * NC + c)) * (NH * NW);

    float m = -INFINITY;
    for (int h = hs; h < he; ++h) {
        const float* __restrict__ row = base + h * NW;
        for (int w = ws; w < we; ++w) {
            m = fmaxf(m, row[w]);
        }
    }
    out[tid] = m;
}

extern "C" void kernel_launch(void* const* d_in, const int* in_sizes, int n_in,
                              void* d_out, int out_size, void* d_ws, size_t ws_size,
                              hipStream_t stream) {
    const float* images  = (const float*)d_in[0];
    const float* rois    = (const float*)d_in[1];
    const int*   roi_idx = (const int*)d_in[2];
    float* out = (float*)d_out;

    const int total = out_size;  // R*C*S*S = 3,211,264 expected
    const int block = 256;
    const int grid = (total + block - 1) / block;
    roipool_kernel<<<grid, block, 0, stream>>>(images, rois, roi_idx, out, total);
}